// Round 5
// baseline (13.786 us; speedup 1.0000x reference)
//
#include <hip/hip_runtime.h>

namespace {
constexpr int IC = 32;
constexpr int OC = 32;
constexpr int HW = 1024;            // 32*32 spatial
constexpr int H2 = 16, W2 = 16;     // pooled dims

typedef _Float16 half2v __attribute__((ext_vector_type(2)));

#if defined(__has_builtin)
#if __has_builtin(__builtin_amdgcn_fdot2)
#define HAVE_FDOT2 1
#endif
#endif

__device__ __forceinline__ float dot2acc(half2v a, half2v b, float c) {
#ifdef HAVE_FDOT2
    return __builtin_amdgcn_fdot2(a, b, c, false);   // v_dot2_f32_f16
#else
    return fmaf((float)a.x, (float)b.x, fmaf((float)a.y, (float)b.y, c));
#endif
}

__device__ __forceinline__ half2v u2h(unsigned int u) {
    union { unsigned int u; half2v h; } x; x.u = u; return x.h;
}

__device__ __forceinline__ unsigned int pk2u(float a, float b) {
    union { decltype(__builtin_amdgcn_cvt_pkrtz(0.f, 0.f)) p; unsigned int u; } x;
    x.p = __builtin_amdgcn_cvt_pkrtz(a, b);   // v_cvt_pkrtz_f16_f32
    return x.u;
}
}

// Block = 256 threads (4 waves), tile 8n x 8o x one strip (2 h-rows x 32 w = 64 pos).
// Grid 512 = 32 tiles x 16 strips; bid = tt*16 + s -> XCD(bid%8)=s%8 keeps a strip's
// x/logits re-reads on one XCD's L2. LDS 66 KB -> 2 blocks/CU.
// R3 phase skeleton (measured best): stage(w full + x chunk0) -> bar ->
// prefetch x chunk1 -> compute GG0,GG1 -> restage chunk1 -> bar -> compute GG2,GG3.
// NEW vs R3: wave tile 4n x 4o (acc 4x4) -> compute LDS reads per output HALVED
// (8 b128 per GG for 16 outputs vs 6 for 8). Denominators accumulated in registers
// during w staging (shfl-reduce over kk lanes, float4 wsl write) -> den LDS-read
// pass deleted. Staged writes widened: w rows = ds_write_b128 (ip=kk*4+g),
// x rows = ds_write_b64 (ip=2kk+g); read-side layout identical to R3:
//   h2 index of (row,p,ip) = (row*64+p)*16 + ((ip>>2)^sw(p))*4 + (ip&3),
//   sw(p) = ((p>>1)^(p>>3))&3 -> compute reads conflict-free ds_read_b128.
__global__ __launch_bounds__(256, 2) void sumprod_fused(
    const float* __restrict__ x, const float* __restrict__ logits,
    float* __restrict__ out)
{
    __shared__ half2v exl[8 * 64 * 16];   // exp(x)   [n8][p64][16 ip slots] 32 KB
    __shared__ half2v ewl[8 * 64 * 16];   // exp(lgt) [o8][p64][16 ip slots] 32 KB
    __shared__ __align__(16) float wsl[8 * 64];  // softmax denominators [o8][p64]

    const int tid  = threadIdx.x;
    const int lane = tid & 63;
    const int v    = tid >> 6;          // wave id 0..3
    const int bid  = blockIdx.x;
    const int s    = bid & 15;          // strip (== h2)
    const int tt   = bid >> 4;          // 0..31
    const int n0   = (tt & 7) * 8;
    const int o0   = (tt >> 3) * 8;

    const int kk    = (tid >> 4) & 3;   // i-subrange selector
    const int p4    = tid & 15;         // float4 slot in strip
    const int pbase = (p4 >> 3) * 32 + (p4 & 7) * 4;
    const int spoff = 2 * s * 32 + pbase;            // elem offset in plane

    // ---- W STAGING: rows o0+v, o0+v+4; ip = kk*4+g (g=0..3) -> b128 writes.
    // Also accumulate softmax denominators in registers (f32, pre-pack).
    float dsum[2][4] = {};
    #pragma unroll
    for (int rr = 0; rr < 2; ++rr) {
        const int r = v + rr * 4;
        const float* g = logits + (size_t)(o0 + r) * IC * HW + spoff;
        float4 va[4], vb[4];
        #pragma unroll
        for (int gi = 0; gi < 4; ++gi) {
            const int ip = kk * 4 + gi;
            va[gi] = *reinterpret_cast<const float4*>(&g[(2 * ip) * HW]);
            vb[gi] = *reinterpret_cast<const float4*>(&g[(2 * ip + 1) * HW]);
        }
        #pragma unroll
        for (int j = 0; j < 4; ++j) {
            const int p    = pbase + j;
            const int slot = kk ^ (((p >> 1) ^ (p >> 3)) & 3);
            uint4 wv;
            unsigned int* wp = &wv.x;
            #pragma unroll
            for (int gi = 0; gi < 4; ++gi) {
                const float ea = __expf(reinterpret_cast<const float*>(&va[gi])[j]);
                const float eb = __expf(reinterpret_cast<const float*>(&vb[gi])[j]);
                dsum[rr][j] += ea + eb;
                wp[gi] = pk2u(ea, eb);
            }
            *reinterpret_cast<uint4*>(&ewl[(r * 64 + p) * 16 + slot * 4]) = wv;
        }
    }
    // reduce dsum over the 4 kk lane-groups (lane bits 4,5) and publish to wsl
    #pragma unroll
    for (int rr = 0; rr < 2; ++rr) {
        #pragma unroll
        for (int j = 0; j < 4; ++j) {
            float d = dsum[rr][j];
            d += __shfl_xor(d, 16);
            d += __shfl_xor(d, 32);
            dsum[rr][j] = d;
        }
        if (kk == 0) {
            float4 dv = make_float4(dsum[rr][0], dsum[rr][1], dsum[rr][2], dsum[rr][3]);
            *reinterpret_cast<float4*>(&wsl[(v + rr * 4) * 64 + pbase]) = dv;
        }
    }

    // ---- X STAGING chunk 0: rows n0+v, n0+v+4; ip = 2kk+g (g=0,1) -> b64 writes
    const float* gx0 = x + (size_t)(n0 + v) * IC * HW + spoff;
    const float* gx1 = x + (size_t)(n0 + v + 4) * IC * HW + spoff;
    #pragma unroll
    for (int rr = 0; rr < 2; ++rr) {
        const int r = v + rr * 4;
        const float* gxr = rr ? gx1 : gx0;
        float4 a0 = *reinterpret_cast<const float4*>(&gxr[(4 * kk + 0) * HW]);
        float4 b0 = *reinterpret_cast<const float4*>(&gxr[(4 * kk + 1) * HW]);
        float4 a1 = *reinterpret_cast<const float4*>(&gxr[(4 * kk + 2) * HW]);
        float4 b1 = *reinterpret_cast<const float4*>(&gxr[(4 * kk + 3) * HW]);
        #pragma unroll
        for (int j = 0; j < 4; ++j) {
            const int p    = pbase + j;
            const int slot = (kk >> 1) ^ (((p >> 1) ^ (p >> 3)) & 3);
            uint2 wv;
            wv.x = pk2u(__expf(reinterpret_cast<const float*>(&a0)[j]),
                        __expf(reinterpret_cast<const float*>(&b0)[j]));
            wv.y = pk2u(__expf(reinterpret_cast<const float*>(&a1)[j]),
                        __expf(reinterpret_cast<const float*>(&b1)[j]));
            *reinterpret_cast<uint2*>(
                &exl[(r * 64 + p) * 16 + slot * 4 + (kk & 1) * 2]) = wv;
        }
    }
    __syncthreads();   // barrier 1

    // ---- prefetch x chunk 1 (ip = 8+2kk+g) into registers; lands under GG0/GG1
    float4 pf[2][4];
    #pragma unroll
    for (int rr = 0; rr < 2; ++rr) {
        const float* gxr = rr ? gx1 : gx0;
        pf[rr][0] = *reinterpret_cast<const float4*>(&gxr[(16 + 4 * kk + 0) * HW]);
        pf[rr][1] = *reinterpret_cast<const float4*>(&gxr[(16 + 4 * kk + 1) * HW]);
        pf[rr][2] = *reinterpret_cast<const float4*>(&gxr[(16 + 4 * kk + 2) * HW]);
        pf[rr][3] = *reinterpret_cast<const float4*>(&gxr[(16 + 4 * kk + 3) * HW]);
    }

    // ---- compute: wave tile 4n x 4o, lane = position
    const int swl = ((lane >> 1) ^ (lane >> 3)) & 3;
    const int nw = (v & 1) * 4;
    const int ow = (v >> 1) * 4;
    float acc[4][4] = {};

#define D2(AA, BB, K, J) acc[K][J] = dot2acc(u2h(AA), u2h(BB), acc[K][J])
#define OCT(A_, K_)                                                           \
    D2(A_.x, B0.x, K_, 0); D2(A_.y, B0.y, K_, 0); D2(A_.z, B0.z, K_, 0); D2(A_.w, B0.w, K_, 0); \
    D2(A_.x, B1.x, K_, 1); D2(A_.y, B1.y, K_, 1); D2(A_.z, B1.z, K_, 1); D2(A_.w, B1.w, K_, 1); \
    D2(A_.x, B2.x, K_, 2); D2(A_.y, B2.y, K_, 2); D2(A_.z, B2.z, K_, 2); D2(A_.w, B2.w, K_, 2); \
    D2(A_.x, B3.x, K_, 3); D2(A_.y, B3.y, K_, 3); D2(A_.z, B3.z, K_, 3); D2(A_.w, B3.w, K_, 3)
#define COMPUTE_GG(GG) {                                                      \
    const int off = ((GG) ^ swl) * 4;                                         \
    const uint4 A0 = *reinterpret_cast<const uint4*>(&exl[((nw + 0) * 64 + lane) * 16 + off]); \
    const uint4 A1 = *reinterpret_cast<const uint4*>(&exl[((nw + 1) * 64 + lane) * 16 + off]); \
    const uint4 A2 = *reinterpret_cast<const uint4*>(&exl[((nw + 2) * 64 + lane) * 16 + off]); \
    const uint4 A3 = *reinterpret_cast<const uint4*>(&exl[((nw + 3) * 64 + lane) * 16 + off]); \
    const uint4 B0 = *reinterpret_cast<const uint4*>(&ewl[((ow + 0) * 64 + lane) * 16 + off]); \
    const uint4 B1 = *reinterpret_cast<const uint4*>(&ewl[((ow + 1) * 64 + lane) * 16 + off]); \
    const uint4 B2 = *reinterpret_cast<const uint4*>(&ewl[((ow + 2) * 64 + lane) * 16 + off]); \
    const uint4 B3 = *reinterpret_cast<const uint4*>(&ewl[((ow + 3) * 64 + lane) * 16 + off]); \
    OCT(A0, 0); OCT(A1, 1); OCT(A2, 2); OCT(A3, 3); }

    COMPUTE_GG(0);
    COMPUTE_GG(1);

    // ---- restage x chunk 1 (slot groups 2,3: disjoint from GG0/GG1 reads)
    #pragma unroll
    for (int rr = 0; rr < 2; ++rr) {
        const int r = v + rr * 4;
        #pragma unroll
        for (int j = 0; j < 4; ++j) {
            const int p    = pbase + j;
            const int slot = (2 + (kk >> 1)) ^ (((p >> 1) ^ (p >> 3)) & 3);
            uint2 wv;
            wv.x = pk2u(__expf(reinterpret_cast<const float*>(&pf[rr][0])[j]),
                        __expf(reinterpret_cast<const float*>(&pf[rr][1])[j]));
            wv.y = pk2u(__expf(reinterpret_cast<const float*>(&pf[rr][2])[j]),
                        __expf(reinterpret_cast<const float*>(&pf[rr][3])[j]));
            *reinterpret_cast<uint2*>(
                &exl[(r * 64 + p) * 16 + slot * 4 + (kk & 1) * 2]) = wv;
        }
    }
    __syncthreads();   // barrier 2

    COMPUTE_GG(2);
    COMPUTE_GG(3);

#undef COMPUTE_GG
#undef OCT
#undef D2

    // ---- epilogue: log, subtract log-denominator, 2x2 pool via shuffles
    float lw[4];
    #pragma unroll
    for (int jj = 0; jj < 4; ++jj)
        lw[jj] = __logf(wsl[(ow + jj) * 64 + lane]);

    #pragma unroll
    for (int k = 0; k < 4; ++k) {
        #pragma unroll
        for (int jj = 0; jj < 4; ++jj) {
            float val = __logf(acc[k][jj]) - lw[jj];
            val += __shfl_xor(val, 1);    // pool over w-pair
            val += __shfl_xor(val, 32);   // pool over h-pair
            if ((lane & 33) == 0) {       // even lane, h_lo == 0
                const int w2 = (lane >> 1) & 15;
                out[((n0 + nw + k) * OC + (o0 + ow + jj)) * (H2 * W2) + s * W2 + w2] = val;
            }
        }
    }
}

extern "C" void kernel_launch(void* const* d_in, const int* in_sizes, int n_in,
                              void* d_out, int out_size, void* d_ws, size_t ws_size,
                              hipStream_t stream) {
    const float* x      = (const float*)d_in[0];
    const float* logits = (const float*)d_in[1];
    float* out = (float*)d_out;
    hipLaunchKernelGGL(sumprod_fused, dim3(512), dim3(256), 0, stream,
                       x, logits, out);
}

// Round 6
// 12.675 us; speedup vs baseline: 1.0876x; 1.0876x over previous
//
#include <hip/hip_runtime.h>

namespace {
constexpr int IC = 32;
constexpr int OC = 32;
constexpr int HW = 1024;            // 32*32 spatial
constexpr int H2 = 16, W2 = 16;     // pooled dims

typedef _Float16 half2v __attribute__((ext_vector_type(2)));

#if defined(__has_builtin)
#if __has_builtin(__builtin_amdgcn_fdot2)
#define HAVE_FDOT2 1
#endif
#endif

__device__ __forceinline__ float dot2acc(half2v a, half2v b, float c) {
#ifdef HAVE_FDOT2
    return __builtin_amdgcn_fdot2(a, b, c, false);   // v_dot2_f32_f16
#else
    return fmaf((float)a.x, (float)b.x, fmaf((float)a.y, (float)b.y, c));
#endif
}

__device__ __forceinline__ half2v u2h(unsigned int u) {
    union { unsigned int u; half2v h; } x; x.u = u; return x.h;
}

__device__ __forceinline__ half2v pk2(float a, float b) {
    union { decltype(__builtin_amdgcn_cvt_pkrtz(0.f, 0.f)) p; half2v h; } x;
    x.p = __builtin_amdgcn_cvt_pkrtz(a, b);   // v_cvt_pkrtz_f16_f32
    return x.h;
}
}

// === R3 structure (best measured: 12.68 us) — restored verbatim. ===
// Block = 512 threads (8 waves), tile 8n x 8o x one strip (2 h-rows x 32 w = 64 pos).
// Grid 512 = 32 tiles x 16 strips; bid = tt*16 + s -> XCD(bid%8)=s%8 keeps a strip's
// x/logits re-reads on one XCD's L2.
// LDS 66 KB -> 2 blocks/CU (two barrier domains overlap stage/compute phases).
// exp values stored as packed f16 pairs; inner product via v_dot2_f32_f16.
// Phase skeleton: stage(w full + x chunk0) -> bar -> prefetch x chunk1 ->
// den pass (fills prefetch latency) -> compute GG0,GG1 -> restage chunk1 (slots
// disjoint from GG0/GG1 reads) -> bar -> compute GG2,GG3 -> epilogue.
// Session evidence: removing the mid barrier (R4) or halving LDS reads/output (R5)
// both REGRESS -> remaining wall time is a fixed launch/graph floor, not pipe work.
__global__ __launch_bounds__(512, 4) void sumprod_fused(
    const float* __restrict__ x, const float* __restrict__ logits,
    float* __restrict__ out)
{
    __shared__ half2v exl[8 * 64 * 16];   // exp(x)   [n8][p64][16 ip slots] 32 KB
    __shared__ half2v ewl[8 * 64 * 16];   // exp(lgt) [o8][p64][16 ip slots] 32 KB
    __shared__ float  wsl[8 * 64];        // softmax denominators [o8][p64]

    const int tid  = threadIdx.x;
    const int lane = tid & 63;
    const int w    = tid >> 6;          // wave id = staging row (n and o)
    const int bid  = blockIdx.x;
    const int s    = bid & 15;          // strip (== h2)
    const int tt   = bid >> 4;          // 0..31
    const int n0   = (tt & 7) * 8;
    const int o0   = (tt >> 3) * 8;

    const int kk    = (tid >> 4) & 3;   // element slot within b128 group
    const int p4    = tid & 15;         // float4 slot in strip
    const int spoff = (2 * s + (p4 >> 3)) * 32 + (p4 & 7) * 4;

    const float* gx = x      + (size_t)(n0 + w) * IC * HW + spoff;
    const float* gw = logits + (size_t)(o0 + w) * IC * HW + spoff;

    // exp + pack f16 pair + swizzled LDS write of one float4-pair task
    auto stage = [&](half2v* buf, const float4& va, const float4& vb, int ip) {
        const float* pa = reinterpret_cast<const float*>(&va);
        const float* pb = reinterpret_cast<const float*>(&vb);
        #pragma unroll
        for (int j = 0; j < 4; ++j) {
            const int p    = (p4 >> 3) * 32 + (p4 & 7) * 4 + j;
            const int slot = (ip >> 2) ^ (((p >> 1) ^ (p >> 3)) & 3);
            buf[(w * 64 + p) * 16 + slot * 4 + (ip & 3)] =
                pk2(__expf(pa[j]), __expf(pb[j]));
        }
    };

    // ---- stage exp(logits) full (ip 0..15) + exp(x) chunk 0 (ip 0..7)
    #pragma unroll
    for (int g = 0; g < 4; ++g) {
        const int ip = g * 4 + kk;
        const float4 va = *reinterpret_cast<const float4*>(&gw[(2 * ip) * HW]);
        const float4 vb = *reinterpret_cast<const float4*>(&gw[(2 * ip + 1) * HW]);
        stage(ewl, va, vb, ip);
    }
    #pragma unroll
    for (int g = 0; g < 2; ++g) {
        const int ip = g * 4 + kk;
        const float4 va = *reinterpret_cast<const float4*>(&gx[(2 * ip) * HW]);
        const float4 vb = *reinterpret_cast<const float4*>(&gx[(2 * ip + 1) * HW]);
        stage(exl, va, vb, ip);
    }
    __syncthreads();

    // ---- prefetch x chunk 1 (ip 8..15) into registers; lands under compute-0
    float4 pva[2], pvb[2];
    #pragma unroll
    for (int g = 0; g < 2; ++g) {
        const int ip = (g + 2) * 4 + kk;
        pva[g] = *reinterpret_cast<const float4*>(&gx[(2 * ip) * HW]);
        pvb[g] = *reinterpret_cast<const float4*>(&gx[(2 * ip + 1) * HW]);
    }

    const int swl = ((lane >> 1) ^ (lane >> 3)) & 3;

    // ---- softmax denominators: thread (o=w, p=lane), conflict-free b128 reads
    {
        float ds = 0.f;
        const half2v one2 = {(_Float16)1.f, (_Float16)1.f};
        #pragma unroll
        for (int gg = 0; gg < 4; ++gg) {
            const uint4 B = *reinterpret_cast<const uint4*>(
                &ewl[(w * 64 + lane) * 16 + ((gg ^ swl) * 4)]);
            ds = dot2acc(u2h(B.x), one2, ds);
            ds = dot2acc(u2h(B.y), one2, ds);
            ds = dot2acc(u2h(B.z), one2, ds);
            ds = dot2acc(u2h(B.w), one2, ds);
        }
        wsl[w * 64 + lane] = ds;
    }

    // ---- compute: wave tile 4n x 2o, lane = position
    const int nw = (w & 1) * 4;
    const int ow = (w >> 1) * 2;
    float acc[4][2] = {};

#define D2(AA, BB, K, J) acc[K][J] = dot2acc(u2h(AA), u2h(BB), acc[K][J])
#define QUAD(A_, K_)                                                          \
    D2(A_.x, B0.x, K_, 0); D2(A_.y, B0.y, K_, 0);                             \
    D2(A_.z, B0.z, K_, 0); D2(A_.w, B0.w, K_, 0);                             \
    D2(A_.x, B1.x, K_, 1); D2(A_.y, B1.y, K_, 1);                             \
    D2(A_.z, B1.z, K_, 1); D2(A_.w, B1.w, K_, 1)
#define COMPUTE_GG(GG) {                                                      \
    const int off = ((GG) ^ swl) * 4;                                         \
    const uint4 A0 = *reinterpret_cast<const uint4*>(&exl[((nw + 0) * 64 + lane) * 16 + off]); \
    const uint4 A1 = *reinterpret_cast<const uint4*>(&exl[((nw + 1) * 64 + lane) * 16 + off]); \
    const uint4 A2 = *reinterpret_cast<const uint4*>(&exl[((nw + 2) * 64 + lane) * 16 + off]); \
    const uint4 A3 = *reinterpret_cast<const uint4*>(&exl[((nw + 3) * 64 + lane) * 16 + off]); \
    const uint4 B0 = *reinterpret_cast<const uint4*>(&ewl[((ow + 0) * 64 + lane) * 16 + off]); \
    const uint4 B1 = *reinterpret_cast<const uint4*>(&ewl[((ow + 1) * 64 + lane) * 16 + off]); \
    QUAD(A0, 0); QUAD(A1, 1); QUAD(A2, 2); QUAD(A3, 3); }

    COMPUTE_GG(0);
    COMPUTE_GG(1);

    // ---- write x chunk 1 (slots g=2,3; disjoint from chunk-0 reads -> no barrier
    // needed before, only after). exp applied now; loads landed under compute-0.
    #pragma unroll
    for (int g = 0; g < 2; ++g) {
        const int ip = (g + 2) * 4 + kk;
        stage(exl, pva[g], pvb[g], ip);
    }
    __syncthreads();

    COMPUTE_GG(2);
    COMPUTE_GG(3);

#undef COMPUTE_GG
#undef QUAD
#undef D2

    // ---- epilogue: log, subtract pooled log-denominator, 2x2 pool via shuffles
    const float lw0 = __logf(wsl[(ow + 0) * 64 + lane]);
    const float lw1 = __logf(wsl[(ow + 1) * 64 + lane]);

    #pragma unroll
    for (int k = 0; k < 4; ++k) {
        #pragma unroll
        for (int j = 0; j < 2; ++j) {
            float v = __logf(acc[k][j]) - (j ? lw1 : lw0);
            v += __shfl_xor(v, 1);    // pool over w-pair
            v += __shfl_xor(v, 32);   // pool over h-pair
            if ((lane & 33) == 0) {   // even lane, h_lo == 0
                const int w2 = (lane >> 1) & 15;
                out[((n0 + nw + k) * OC + (o0 + ow + j)) * (H2 * W2) + s * W2 + w2] = v;
            }
        }
    }
}

extern "C" void kernel_launch(void* const* d_in, const int* in_sizes, int n_in,
                              void* d_out, int out_size, void* d_ws, size_t ws_size,
                              hipStream_t stream) {
    const float* x      = (const float*)d_in[0];
    const float* logits = (const float*)d_in[1];
    float* out = (float*)d_out;
    hipLaunchKernelGGL(sumprod_fused, dim3(512), dim3(512), 0, stream,
                       x, logits, out);
}